// Round 5
// baseline (470.002 us; speedup 1.0000x reference)
//
#include <hip/hip_runtime.h>
#include <math.h>

#ifndef M_PI
#define M_PI 3.14159265358979323846
#endif

#define T_LEN 4096
#define M_LEN 2048   // T/2, complex FFT length
#define NFREQ 2049   // T/2 + 1
#define KM 8         // modes
#define LI 8         // iterations
#define CD 16        // channels

// ---------------- complex helpers ----------------
__device__ __forceinline__ float2 cadd(float2 a, float2 b){ return make_float2(a.x+b.x, a.y+b.y); }
__device__ __forceinline__ float2 csub(float2 a, float2 b){ return make_float2(a.x-b.x, a.y-b.y); }
__device__ __forceinline__ float2 cmul(float2 a, float2 b){ return make_float2(a.x*b.x - a.y*b.y, a.x*b.y + a.y*b.x); }
#define RC 0.70710678118654752440f

// SGN = +1: inverse (e^{+i...}); SGN = -1: forward (e^{-i...}).
template<int SGN>
__device__ __forceinline__ float2 muli_s(float2 a){   // * (SGN * i)
    return (SGN > 0) ? make_float2(-a.y, a.x) : make_float2(a.y, -a.x);
}
template<int SGN>
__device__ __forceinline__ float2 w81_s(float2 a){    // * (c + SGN*ic)
    return (SGN > 0) ? make_float2(RC*(a.x-a.y), RC*(a.x+a.y))
                     : make_float2(RC*(a.x+a.y), RC*(a.y-a.x));
}
template<int SGN>
__device__ __forceinline__ float2 w83_s(float2 a){    // * (-c + SGN*ic)
    return (SGN > 0) ? make_float2(-RC*(a.x+a.y), RC*(a.x-a.y))
                     : make_float2(RC*(a.y-a.x), -RC*(a.x+a.y));
}

// LDS XOR swizzle on float2 index (bijective; bank-conflict fix validated in
// r4: SQ_LDS_BANK_CONFLICT 4.19M -> 1.56M).
#define SWZ(i) ((i) ^ (((i) >> 4) & 15))

// 8-point DFT, sign-templated, natural order in/out.
template<int SGN>
__device__ __forceinline__ void dft8_s(const float2 a[8], float2 x[8]) {
    float2 s0=cadd(a[0],a[4]), s1=cadd(a[1],a[5]), s2=cadd(a[2],a[6]), s3=cadd(a[3],a[7]);
    float2 d0=csub(a[0],a[4]), d1=csub(a[1],a[5]), d2=csub(a[2],a[6]), d3=csub(a[3],a[7]);
    d1 = w81_s<SGN>(d1); d2 = muli_s<SGN>(d2); d3 = w83_s<SGN>(d3);
    float2 e0=cadd(s0,s2), e2=csub(s0,s2), e1=cadd(s1,s3), e3=muli_s<SGN>(csub(s1,s3));
    float2 f0=cadd(d0,d2), f2=csub(d0,d2), f1=cadd(d1,d3), f3=muli_s<SGN>(csub(d1,d3));
    x[0]=cadd(e0,e1); x[4]=csub(e0,e1); x[2]=cadd(e2,e3); x[6]=csub(e2,e3);
    x[1]=cadd(f0,f1); x[5]=csub(f0,f1); x[3]=cadd(f2,f3); x[7]=csub(f2,f3);
}

// One Stockham radix-8 stage, in-place via regs + 2 barriers. 256 threads/2048 pts.
// Reads S[i + k*256], writes S[(i%m) + (8*(i/m)+k)*m], twiddle W_2048^{SGN*k*j*m}.
template<int MSTAGE, int SGN>
__device__ __forceinline__ void r8_stage(float2* S, int lt) {
    float2 a[8];
    #pragma unroll
    for (int k = 0; k < 8; ++k) a[k] = S[SWZ(lt + 256*k)];
    __syncthreads();
    float2 x[8];
    dft8_s<SGN>(a, x);
    const int j = lt / MSTAGE;
    const int r = lt % MSTAGE;
    float th = (float)SGN * ((float)M_PI / 1024.0f) * (float)(j * MSTAGE);
    float swv, cwv; __sincosf(th, &swv, &cwv);
    float2 w1 = make_float2(cwv, swv);
    float2 w2 = cmul(w1,w1), w3 = cmul(w2,w1), w4 = cmul(w2,w2);
    float2 w5 = cmul(w3,w2), w6 = cmul(w3,w3), w7 = cmul(w4,w3);
    x[1]=cmul(x[1],w1); x[2]=cmul(x[2],w2); x[3]=cmul(x[3],w3);
    x[4]=cmul(x[4],w4); x[5]=cmul(x[5],w5); x[6]=cmul(x[6],w6); x[7]=cmul(x[7],w7);
    const int base = r + 8*MSTAGE*j;
    #pragma unroll
    for (int k = 0; k < 8; ++k) S[SWZ(base + MSTAGE*k)] = x[k];
    __syncthreads();
}

// Final radix-4 stage (m=512, j=0 -> twiddle-free), 2 butterflies/thread, in place.
template<int SGN>
__device__ __forceinline__ void r4_stage_pair(float2* S, int lt) {
    float2 b[2][4];
    #pragma unroll
    for (int h = 0; h < 2; ++h) {
        int i2 = lt + 256*h;
        #pragma unroll
        for (int k = 0; k < 4; ++k) b[h][k] = S[SWZ(i2 + 512*k)];
    }
    __syncthreads();
    #pragma unroll
    for (int h = 0; h < 2; ++h) {
        int i2 = lt + 256*h;
        float2 s02=cadd(b[h][0],b[h][2]), d02=csub(b[h][0],b[h][2]);
        float2 s13=cadd(b[h][1],b[h][3]), d13=muli_s<SGN>(csub(b[h][1],b[h][3]));
        S[SWZ(i2 +    0)] = cadd(s02,s13);
        S[SWZ(i2 +  512)] = cadd(d02,d13);
        S[SWZ(i2 + 1024)] = csub(s02,s13);
        S[SWZ(i2 + 1536)] = csub(d02,d13);
    }
    __syncthreads();
}

// K1: 512 threads, 2 rows (b,c) per block (256 threads each). Forward radix-8
// rfft (engine validated by r4's PASS; forward = conjugated constants) + Jacobi.
__global__ void __launch_bounds__(512)
k_fwd_iter(const float* __restrict__ x,
           const float* __restrict__ log_alpha,
           const float* __restrict__ raw_tau,
           const float* __restrict__ raw_omega,
           float2* __restrict__ u_ws)
{
    __shared__ float2 S[2][M_LEN];    // 32 KB
    __shared__ float s_2a[LI * KM];
    __shared__ float s_tau[LI];
    __shared__ float s_om[KM];

    const int tid = threadIdx.x;
    const int g   = tid >> 8;         // row slot 0..1
    const int lt  = tid & 255;
    const int row = blockIdx.x * 2 + g;   // b*16 + c
    const int b = row >> 4;
    const int c = row & 15;

    if (tid < LI * KM) s_2a[tid] = 2.0f * __expf(log_alpha[tid]);
    if (tid < LI)      s_tau[tid] = log1pf(__expf(raw_tau[tid]));
    if (tid < KM)      s_om[tid]  = 0.5f / (1.0f + __expf(-raw_omega[tid]));

    // pack z[n] = x[2n] + i*x[2n+1]
    const float* xr = x + (size_t)b * T_LEN * CD + c;
    #pragma unroll
    for (int q = 0; q < 8; ++q) {
        int n = lt + 256 * q;
        float e = xr[(size_t)(2 * n) * CD];
        float o = xr[(size_t)(2 * n + 1) * CD];
        S[g][SWZ(n)] = make_float2(e, o);
    }
    __syncthreads();

    r8_stage<1,  -1>(S[g], lt);
    r8_stage<8,  -1>(S[g], lt);
    r8_stage<64, -1>(S[g], lt);
    r4_stage_pair<-1>(S[g], lt);      // S[g] now holds forward FFT Z (swizzled)

    const size_t sb = (size_t)(b * (KM * CD) + c);

    for (int f = lt; f < NFREQ; f += 256) {
        float2 Zk = S[g][SWZ(f & (M_LEN - 1))];
        float2 Zm = S[g][SWZ((M_LEN - f) & (M_LEN - 1))];
        float2 E = make_float2(0.5f * (Zk.x + Zm.x), 0.5f * (Zk.y - Zm.y));
        float2 D = make_float2(0.5f * (Zk.x - Zm.x), 0.5f * (Zk.y + Zm.y));
        float2 O = make_float2(D.y, -D.x);
        float ang = -2.0f * (float)M_PI * (float)f / (float)T_LEN;
        float sw, cw;
        __sincosf(ang, &sw, &cw);
        float fhx = E.x + cw * O.x - sw * O.y;
        float fhy = E.y + cw * O.y + sw * O.x;

        float freq = (float)f * (0.5f / (float)M_LEN);
        float dd[KM];
        #pragma unroll
        for (int k = 0; k < KM; ++k) {
            float d = freq - s_om[k];
            dd[k] = d * d;
        }

        float2 u[KM];
        #pragma unroll
        for (int k = 0; k < KM; ++k) u[k] = make_float2(0.f, 0.f);
        float lamx = 0.f, lamy = 0.f;

        #pragma unroll
        for (int l = 0; l < LI; ++l) {
            float usx = 0.f, usy = 0.f;
            #pragma unroll
            for (int k = 0; k < KM; ++k) { usx += u[k].x; usy += u[k].y; }
            float bx = fhx - usx + 0.5f * lamx;
            float by = fhy - usy + 0.5f * lamy;
            float sx = 0.f, sy = 0.f;
            #pragma unroll
            for (int k = 0; k < KM; ++k) {
                float den = fmaf(s_2a[l * KM + k], dd[k], 1.0f);
                float r = __builtin_amdgcn_rcpf(den);
                float ux = (bx + u[k].x) * r;
                float uy = (by + u[k].y) * r;
                u[k].x = ux; u[k].y = uy;
                sx += ux; sy += uy;
            }
            lamx += s_tau[l] * (fhx - sx);
            lamy += s_tau[l] * (fhy - sy);
        }

        #pragma unroll
        for (int k = 0; k < KM; ++k) {
            u_ws[(sb + (size_t)k * CD) * NFREQ + f] = u[k];
        }
    }
}

// K2: one block per (b,k). 16 inverse rffts as 4 passes x 4 channels.
// r4 fix #1: per-pass stores (pass cp = float4 column cp of each thread's
//   output chunk) -> no cross-pass register state (r4 spilled 64-float val[]).
// r4 fix #2: LDS-staged fill (1x coalesced u_ws read) + IN-PLACE conjugate
//   repack: each (j, 2048-j) slot pair is read and written by exactly one
//   thread, so no barrier inside the repack.
__global__ void __launch_bounds__(1024)
k_inv(const float2* __restrict__ u_ws, float* __restrict__ out)
{
    __shared__ float2 S[4][M_LEN];    // 64 KB, swizzled indexing

    const int tid = threadIdx.x;
    const int g   = tid >> 8;         // channel slot 0..3
    const int lt  = tid & 255;
    const int bk  = blockIdx.x;       // b*8 + k

    const float sc = 1.0f / (float)M_LEN;
    float4* op = (float4*)(out + ((size_t)bk * T_LEN + (size_t)(4 * tid)) * CD);

    #pragma unroll 1
    for (int cp = 0; cp < 4; ++cp) {
        const float2* sp = u_ws + (size_t)(bk * CD + 4 * cp + g) * NFREQ;

        // ---- fill: coalesced 1x read of the spectrum into LDS ----
        #pragma unroll
        for (int q = 0; q < 8; ++q) {
            int n = lt + 256 * q;
            S[g][SWZ(n)] = sp[n];
        }
        __syncthreads();

        // ---- in-place irfft repack (no intra-phase barrier needed) ----
        #pragma unroll
        for (int q = 0; q < 4; ++q) {
            int j = lt + 256 * q;
            float2 Xj = S[g][SWZ(j)];
            float2 Xm = (j > 0) ? S[g][SWZ(M_LEN - j)] : sp[M_LEN];  // Nyquist from global
            float Ex = 0.5f * (Xj.x + Xm.x), Ey = 0.5f * (Xj.y - Xm.y);
            float Dx = 0.5f * (Xj.x - Xm.x), Dy = 0.5f * (Xj.y + Xm.y);
            float ang = (2.0f * (float)M_PI / (float)T_LEN) * (float)j;
            float swv, cwv;
            __sincosf(ang, &swv, &cwv);
            float Ox = cwv * Dx - swv * Dy;
            float Oy = cwv * Dy + swv * Dx;
            if (j > 0) {
                S[g][SWZ(j)]         = make_float2((Ex - Oy) * sc, (Ey + Ox) * sc);
                S[g][SWZ(M_LEN - j)] = make_float2((Ex + Oy) * sc, (Ox - Ey) * sc);
            } else {
                float2 Xq = S[g][SWZ(1024)];        // self-paired bin
                S[g][SWZ(0)]    = make_float2((Ex - Oy) * sc, (Ey + Ox) * sc);
                S[g][SWZ(1024)] = make_float2(Xq.x * sc, -Xq.y * sc);
            }
        }
        __syncthreads();

        // ---- 2048 = 8 * 8 * 8 * 4, inverse sign ----
        r8_stage<1,  1>(S[g], lt);
        r8_stage<8,  1>(S[g], lt);
        r8_stage<64, 1>(S[g], lt);
        r4_stage_pair<1>(S[g], lt);

        // ---- readout + immediate store: channels 4cp..4cp+3 ----
        float v[4][4];
        #pragma unroll
        for (int cc = 0; cc < 4; ++cc) {
            float2 z0 = S[cc][SWZ(2 * tid)];
            float2 z1 = S[cc][SWZ(2 * tid + 1)];
            v[cc][0] = z0.x;   // t = 4*tid + 0
            v[cc][1] = z0.y;   // t = 4*tid + 1
            v[cc][2] = z1.x;
            v[cc][3] = z1.y;
        }
        #pragma unroll
        for (int r = 0; r < 4; ++r) {
            op[r * 4 + cp] = make_float4(v[0][r], v[1][r], v[2][r], v[3][r]);
        }
        __syncthreads();              // before next pass's fill overwrites S
    }
}

extern "C" void kernel_launch(void* const* d_in, const int* in_sizes, int n_in,
                              void* d_out, int out_size, void* d_ws, size_t ws_size,
                              hipStream_t stream) {
    const float* x         = (const float*)d_in[0];
    const float* log_alpha = (const float*)d_in[1];
    const float* raw_tau   = (const float*)d_in[2];
    const float* raw_omega = (const float*)d_in[3];
    float* out = (float*)d_out;
    float2* u_ws = (float2*)d_ws;   // needs 8192 * 2049 * 8 B = 134.3 MB

    k_fwd_iter<<<dim3(64 * CD / 2), dim3(512), 0, stream>>>(x, log_alpha, raw_tau,
                                                            raw_omega, u_ws);
    k_inv<<<dim3(64 * KM), dim3(1024), 0, stream>>>(u_ws, out);
}

// Round 6
// 399.354 us; speedup vs baseline: 1.1769x; 1.1769x over previous
//
#include <hip/hip_runtime.h>
#include <math.h>

#ifndef M_PI
#define M_PI 3.14159265358979323846
#endif

#define T_LEN 4096
#define M_LEN 2048   // T/2, complex FFT length
#define NFREQ 2049   // T/2 + 1
#define KM 8         // modes
#define LI 8         // iterations
#define CD 16        // channels

// ---------------- complex helpers ----------------
__device__ __forceinline__ float2 cadd(float2 a, float2 b){ return make_float2(a.x+b.x, a.y+b.y); }
__device__ __forceinline__ float2 csub(float2 a, float2 b){ return make_float2(a.x-b.x, a.y-b.y); }
__device__ __forceinline__ float2 cmul(float2 a, float2 b){ return make_float2(a.x*b.x - a.y*b.y, a.x*b.y + a.y*b.x); }
#define RC 0.70710678118654752440f

// SGN = +1: inverse (e^{+i...}); SGN = -1: forward (e^{-i...}).
template<int SGN>
__device__ __forceinline__ float2 muli_s(float2 a){   // * (SGN * i)
    return (SGN > 0) ? make_float2(-a.y, a.x) : make_float2(a.y, -a.x);
}
template<int SGN>
__device__ __forceinline__ float2 w81_s(float2 a){    // * (c + SGN*ic)
    return (SGN > 0) ? make_float2(RC*(a.x-a.y), RC*(a.x+a.y))
                     : make_float2(RC*(a.x+a.y), RC*(a.y-a.x));
}
template<int SGN>
__device__ __forceinline__ float2 w83_s(float2 a){    // * (-c + SGN*ic)
    return (SGN > 0) ? make_float2(-RC*(a.x+a.y), RC*(a.x-a.y))
                     : make_float2(RC*(a.y-a.x), -RC*(a.x+a.y));
}

// LDS XOR swizzle on float2 index (bijective; bank-conflict fix validated:
// SQ_LDS_BANK_CONFLICT 4.19M -> 1.56M).
#define SWZ(i) ((i) ^ (((i) >> 4) & 15))

// 8-point DFT, sign-templated, natural order in/out.
template<int SGN>
__device__ __forceinline__ void dft8_s(const float2 a[8], float2 x[8]) {
    float2 s0=cadd(a[0],a[4]), s1=cadd(a[1],a[5]), s2=cadd(a[2],a[6]), s3=cadd(a[3],a[7]);
    float2 d0=csub(a[0],a[4]), d1=csub(a[1],a[5]), d2=csub(a[2],a[6]), d3=csub(a[3],a[7]);
    d1 = w81_s<SGN>(d1); d2 = muli_s<SGN>(d2); d3 = w83_s<SGN>(d3);
    float2 e0=cadd(s0,s2), e2=csub(s0,s2), e1=cadd(s1,s3), e3=muli_s<SGN>(csub(s1,s3));
    float2 f0=cadd(d0,d2), f2=csub(d0,d2), f1=cadd(d1,d3), f3=muli_s<SGN>(csub(d1,d3));
    x[0]=cadd(e0,e1); x[4]=csub(e0,e1); x[2]=cadd(e2,e3); x[6]=csub(e2,e3);
    x[1]=cadd(f0,f1); x[5]=csub(f0,f1); x[3]=cadd(f2,f3); x[7]=csub(f2,f3);
}

// One Stockham radix-8 stage, in-place via regs + 2 barriers. 256 threads/2048 pts.
// Reads S[i + k*256], writes S[(i%m) + (8*(i/m)+k)*m], twiddle W_2048^{SGN*k*j*m}.
template<int MSTAGE, int SGN>
__device__ __forceinline__ void r8_stage(float2* S, int lt) {
    float2 a[8];
    #pragma unroll
    for (int k = 0; k < 8; ++k) a[k] = S[SWZ(lt + 256*k)];
    __syncthreads();
    float2 x[8];
    dft8_s<SGN>(a, x);
    const int j = lt / MSTAGE;
    const int r = lt % MSTAGE;
    float th = (float)SGN * ((float)M_PI / 1024.0f) * (float)(j * MSTAGE);
    float swv, cwv; __sincosf(th, &swv, &cwv);
    float2 w1 = make_float2(cwv, swv);
    float2 w2 = cmul(w1,w1), w3 = cmul(w2,w1), w4 = cmul(w2,w2);
    float2 w5 = cmul(w3,w2), w6 = cmul(w3,w3), w7 = cmul(w4,w3);
    x[1]=cmul(x[1],w1); x[2]=cmul(x[2],w2); x[3]=cmul(x[3],w3);
    x[4]=cmul(x[4],w4); x[5]=cmul(x[5],w5); x[6]=cmul(x[6],w6); x[7]=cmul(x[7],w7);
    const int base = r + 8*MSTAGE*j;
    #pragma unroll
    for (int k = 0; k < 8; ++k) S[SWZ(base + MSTAGE*k)] = x[k];
    __syncthreads();
}

// Final radix-4 stage (m=512, j=0 -> twiddle-free), 2 butterflies/thread, in place.
template<int SGN>
__device__ __forceinline__ void r4_stage_pair(float2* S, int lt) {
    float2 b[2][4];
    #pragma unroll
    for (int h = 0; h < 2; ++h) {
        int i2 = lt + 256*h;
        #pragma unroll
        for (int k = 0; k < 4; ++k) b[h][k] = S[SWZ(i2 + 512*k)];
    }
    __syncthreads();
    #pragma unroll
    for (int h = 0; h < 2; ++h) {
        int i2 = lt + 256*h;
        float2 s02=cadd(b[h][0],b[h][2]), d02=csub(b[h][0],b[h][2]);
        float2 s13=cadd(b[h][1],b[h][3]), d13=muli_s<SGN>(csub(b[h][1],b[h][3]));
        S[SWZ(i2 +    0)] = cadd(s02,s13);
        S[SWZ(i2 +  512)] = cadd(d02,d13);
        S[SWZ(i2 + 1024)] = csub(s02,s13);
        S[SWZ(i2 + 1536)] = csub(d02,d13);
    }
    __syncthreads();
}

// K1: 512 threads, 2 rows (b,c) per block. Forward radix-8 rfft + Jacobi.
// (UNCHANGED this round for attribution; counters next round once k_inv shrinks.)
__global__ void __launch_bounds__(512)
k_fwd_iter(const float* __restrict__ x,
           const float* __restrict__ log_alpha,
           const float* __restrict__ raw_tau,
           const float* __restrict__ raw_omega,
           float2* __restrict__ u_ws)
{
    __shared__ float2 S[2][M_LEN];    // 32 KB
    __shared__ float s_2a[LI * KM];
    __shared__ float s_tau[LI];
    __shared__ float s_om[KM];

    const int tid = threadIdx.x;
    const int g   = tid >> 8;         // row slot 0..1
    const int lt  = tid & 255;
    const int row = blockIdx.x * 2 + g;   // b*16 + c
    const int b = row >> 4;
    const int c = row & 15;

    if (tid < LI * KM) s_2a[tid] = 2.0f * __expf(log_alpha[tid]);
    if (tid < LI)      s_tau[tid] = log1pf(__expf(raw_tau[tid]));
    if (tid < KM)      s_om[tid]  = 0.5f / (1.0f + __expf(-raw_omega[tid]));

    // pack z[n] = x[2n] + i*x[2n+1]
    const float* xr = x + (size_t)b * T_LEN * CD + c;
    #pragma unroll
    for (int q = 0; q < 8; ++q) {
        int n = lt + 256 * q;
        float e = xr[(size_t)(2 * n) * CD];
        float o = xr[(size_t)(2 * n + 1) * CD];
        S[g][SWZ(n)] = make_float2(e, o);
    }
    __syncthreads();

    r8_stage<1,  -1>(S[g], lt);
    r8_stage<8,  -1>(S[g], lt);
    r8_stage<64, -1>(S[g], lt);
    r4_stage_pair<-1>(S[g], lt);      // S[g] now holds forward FFT Z (swizzled)

    const size_t sb = (size_t)(b * (KM * CD) + c);

    for (int f = lt; f < NFREQ; f += 256) {
        float2 Zk = S[g][SWZ(f & (M_LEN - 1))];
        float2 Zm = S[g][SWZ((M_LEN - f) & (M_LEN - 1))];
        float2 E = make_float2(0.5f * (Zk.x + Zm.x), 0.5f * (Zk.y - Zm.y));
        float2 D = make_float2(0.5f * (Zk.x - Zm.x), 0.5f * (Zk.y + Zm.y));
        float2 O = make_float2(D.y, -D.x);
        float ang = -2.0f * (float)M_PI * (float)f / (float)T_LEN;
        float sw, cw;
        __sincosf(ang, &sw, &cw);
        float fhx = E.x + cw * O.x - sw * O.y;
        float fhy = E.y + cw * O.y + sw * O.x;

        float freq = (float)f * (0.5f / (float)M_LEN);
        float dd[KM];
        #pragma unroll
        for (int k = 0; k < KM; ++k) {
            float d = freq - s_om[k];
            dd[k] = d * d;
        }

        float2 u[KM];
        #pragma unroll
        for (int k = 0; k < KM; ++k) u[k] = make_float2(0.f, 0.f);
        float lamx = 0.f, lamy = 0.f;

        #pragma unroll
        for (int l = 0; l < LI; ++l) {
            float usx = 0.f, usy = 0.f;
            #pragma unroll
            for (int k = 0; k < KM; ++k) { usx += u[k].x; usy += u[k].y; }
            float bx = fhx - usx + 0.5f * lamx;
            float by = fhy - usy + 0.5f * lamy;
            float sx = 0.f, sy = 0.f;
            #pragma unroll
            for (int k = 0; k < KM; ++k) {
                float den = fmaf(s_2a[l * KM + k], dd[k], 1.0f);
                float r = __builtin_amdgcn_rcpf(den);
                float ux = (bx + u[k].x) * r;
                float uy = (by + u[k].y) * r;
                u[k].x = ux; u[k].y = uy;
                sx += ux; sy += uy;
            }
            lamx += s_tau[l] * (fhx - sx);
            lamy += s_tau[l] * (fhy - sy);
        }

        #pragma unroll
        for (int k = 0; k < KM; ++k) {
            u_ws[(sb + (size_t)k * CD) * NFREQ + f] = u[k];
        }
    }
}

// ---- one k_inv pass, CP is a TEMPLATE parameter so every val[] index is a
// compile-time constant (r4 lesson: #pragma unroll was silently not honored,
// demoting val[] to memory scratch -> +250 MB FETCH/WRITE).
template<int CP>
__device__ __forceinline__ void inv_pass(const float2* __restrict__ u_ws,
                                         float2 S[4][M_LEN],
                                         int tid, int g, int lt, int bk,
                                         float4 (&val)[CD])
{
    const float sc = 1.0f / (float)M_LEN;
    const float2* sp = u_ws + (size_t)(bk * CD + 4 * CP + g) * NFREQ;

    // fill: coalesced 1x read of the spectrum into LDS
    #pragma unroll
    for (int q = 0; q < 8; ++q) {
        int n = lt + 256 * q;
        S[g][SWZ(n)] = sp[n];
    }
    __syncthreads();

    // in-place irfft repack: thread lt owns slot pairs (j, 2048-j), no hazard
    #pragma unroll
    for (int q = 0; q < 4; ++q) {
        int j = lt + 256 * q;
        float2 Xj = S[g][SWZ(j)];
        float2 Xm = (j > 0) ? S[g][SWZ(M_LEN - j)] : sp[M_LEN];  // Nyquist from global
        float Ex = 0.5f * (Xj.x + Xm.x), Ey = 0.5f * (Xj.y - Xm.y);
        float Dx = 0.5f * (Xj.x - Xm.x), Dy = 0.5f * (Xj.y + Xm.y);
        float ang = (2.0f * (float)M_PI / (float)T_LEN) * (float)j;
        float swv, cwv;
        __sincosf(ang, &swv, &cwv);
        float Ox = cwv * Dx - swv * Dy;
        float Oy = cwv * Dy + swv * Dx;
        if (j > 0) {
            S[g][SWZ(j)]         = make_float2((Ex - Oy) * sc, (Ey + Ox) * sc);
            S[g][SWZ(M_LEN - j)] = make_float2((Ex + Oy) * sc, (Ox - Ey) * sc);
        } else {
            float2 Xq = S[g][SWZ(1024)];        // self-paired bin
            S[g][SWZ(0)]    = make_float2((Ex - Oy) * sc, (Ey + Ox) * sc);
            S[g][SWZ(1024)] = make_float2(Xq.x * sc, -Xq.y * sc);
        }
    }
    __syncthreads();

    // 2048 = 8 * 8 * 8 * 4, inverse sign
    r8_stage<1,  1>(S[g], lt);
    r8_stage<8,  1>(S[g], lt);
    r8_stage<64, 1>(S[g], lt);
    r4_stage_pair<1>(S[g], lt);

    // readout: channels 4*CP .. 4*CP+3, t = 4*tid + {0,1,2,3}
    #pragma unroll
    for (int cc = 0; cc < 4; ++cc) {
        float2 z0 = S[cc][SWZ(2 * tid)];
        float2 z1 = S[cc][SWZ(2 * tid + 1)];
        val[4 * CP + cc] = make_float4(z0.x, z0.y, z1.x, z1.y);
    }
    __syncthreads();              // S free for next pass's fill
}

__device__ __forceinline__ float f4c(float4 v, int r) {
    return r == 0 ? v.x : r == 1 ? v.y : r == 2 ? v.z : v.w;   // r is unroll-const
}

// K2: one block per (b,k). 16 inverse rffts as 4 template-expanded passes x 4
// channels. Cross-pass state val[16] (float4 per channel) is statically indexed
// everywhere -> stays in registers/AGPRs. Final store is r0's proven pattern:
// 256 B contiguous per thread (r5's per-pass 16B-stride-64B stores caused
// partial-line RMW amplification: WRITE 397 MB vs 134 ideal).
// __launch_bounds__(1024, 4): 1024-thr blocks can only run 4 waves/EU; declare
// it so the allocator budget is 128 VGPRs (need ~110) not the 64 heuristic.
__global__ void __launch_bounds__(1024, 4)
k_inv(const float2* __restrict__ u_ws, float* __restrict__ out)
{
    __shared__ float2 S[4][M_LEN];    // 64 KB, swizzled indexing

    const int tid = threadIdx.x;
    const int g   = tid >> 8;         // channel slot 0..3
    const int lt  = tid & 255;
    const int bk  = blockIdx.x;       // b*8 + k

    float4 val[CD];                   // [channel] = out at t offsets 0..3

    inv_pass<0>(u_ws, S, tid, g, lt, bk, val);
    inv_pass<1>(u_ws, S, tid, g, lt, bk, val);
    inv_pass<2>(u_ws, S, tid, g, lt, bk, val);
    inv_pass<3>(u_ws, S, tid, g, lt, bk, val);

    // Each thread owns out[b, k, 4*tid .. 4*tid+3, 0..15]: contiguous 256 B.
    float4* op = (float4*)(out + ((size_t)bk * T_LEN + (size_t)(4 * tid)) * CD);
    #pragma unroll
    for (int r = 0; r < 4; ++r) {
        #pragma unroll
        for (int g2 = 0; g2 < 4; ++g2) {
            op[r * 4 + g2] = make_float4(f4c(val[4 * g2 + 0], r),
                                         f4c(val[4 * g2 + 1], r),
                                         f4c(val[4 * g2 + 2], r),
                                         f4c(val[4 * g2 + 3], r));
        }
    }
}

extern "C" void kernel_launch(void* const* d_in, const int* in_sizes, int n_in,
                              void* d_out, int out_size, void* d_ws, size_t ws_size,
                              hipStream_t stream) {
    const float* x         = (const float*)d_in[0];
    const float* log_alpha = (const float*)d_in[1];
    const float* raw_tau   = (const float*)d_in[2];
    const float* raw_omega = (const float*)d_in[3];
    float* out = (float*)d_out;
    float2* u_ws = (float2*)d_ws;   // needs 8192 * 2049 * 8 B = 134.3 MB

    k_fwd_iter<<<dim3(64 * CD / 2), dim3(512), 0, stream>>>(x, log_alpha, raw_tau,
                                                            raw_omega, u_ws);
    k_inv<<<dim3(64 * KM), dim3(1024), 0, stream>>>(u_ws, out);
}